// Round 15
// baseline (416.839 us; speedup 1.0000x reference)
//
#include <hip/hip_runtime.h>

static constexpr int Hc  = 512;
static constexpr int NHc = 8;
static constexpr int DHc = 64;
static constexpr int NLc = 2;
static constexpr int Rc  = 64;
static constexpr int FFc = 2048;
static constexpr int Bc  = 4;
static constexpr int Tc  = 512;
#define NEGV (-1e10f)
#define EPSV 1e-5f

typedef unsigned short u16;
typedef unsigned char u8;
typedef __attribute__((ext_vector_type(8))) short s16x8;
typedef __attribute__((ext_vector_type(4))) float f32x4;

__device__ __forceinline__ f32x4 mfma_bf16(s16x8 a, s16x8 b, f32x4 c) {
  return __builtin_amdgcn_mfma_f32_16x16x32_bf16(a, b, c, 0, 0, 0);
}
__device__ __forceinline__ u16 f2bf(float f) {
  union { float f; unsigned u; } x; x.f = f;
  unsigned r = (x.u + 0x7FFFu + ((x.u >> 16) & 1u)) >> 16;
  return (u16)r;
}
__device__ __forceinline__ float bf2f(u16 h) {
  union { unsigned u; float f; } x; x.u = ((unsigned)h) << 16;
  return x.f;
}

// ---------------------------------------------------------------------------
// bf16 MFMA GEMM: C[M,N] = A[M,K] @ Wt[N,K]^T (+bias for col<biasN) (+relu)
// Register double-buffer of the next K-tile.
// ---------------------------------------------------------------------------
template <int BM, int BN, bool RELU, int OUT>  // OUT: 0=f32, 1=bf16
__global__ __launch_bounds__(256) void gemm_mfma(
    const u16* __restrict__ A, const u16* __restrict__ Wt,
    const float* __restrict__ bias, int biasN,
    void* __restrict__ Cout, int N, int K) {
  __shared__ u16 As[BM * 32];
  __shared__ u16 Bs[BN * 32];
  const int tid = threadIdx.x;
  const int w = tid >> 6, lane = tid & 63, g = lane >> 4, li = lane & 15;
  const int bn = blockIdx.x * BN, bm = blockIdx.y * BM;
  const int r0 = (w & 1) * (BM / 2), c0 = (w >> 1) * (BN / 2);
  constexpr int MR = BM / 32, NR = BN / 32;
  constexpr int AIT = BM / 64, BIT = BN / 64;
  f32x4 acc[MR][NR];
#pragma unroll
  for (int i = 0; i < MR; ++i)
#pragma unroll
    for (int j = 0; j < NR; ++j) acc[i][j] = (f32x4){0.f, 0.f, 0.f, 0.f};

  s16x8 va[AIT], vb[BIT];
#pragma unroll
  for (int it = 0; it < AIT; ++it) {
    int s = it * 256 + tid, row = s >> 2, ch = s & 3;
    va[it] = *(const s16x8*)(A + (size_t)(bm + row) * K + ch * 8);
  }
#pragma unroll
  for (int it = 0; it < BIT; ++it) {
    int s = it * 256 + tid, row = s >> 2, ch = s & 3;
    vb[it] = *(const s16x8*)(Wt + (size_t)(bn + row) * K + ch * 8);
  }

  for (int k0 = 0; k0 < K; k0 += 32) {
    __syncthreads();
#pragma unroll
    for (int it = 0; it < AIT; ++it) {
      int s = it * 256 + tid, row = s >> 2, ch = s & 3;
      *(s16x8*)&As[row * 32 + ((ch ^ (row & 3)) * 8)] = va[it];
    }
#pragma unroll
    for (int it = 0; it < BIT; ++it) {
      int s = it * 256 + tid, row = s >> 2, ch = s & 3;
      *(s16x8*)&Bs[row * 32 + ((ch ^ (row & 3)) * 8)] = vb[it];
    }
    if (k0 + 32 < K) {
#pragma unroll
      for (int it = 0; it < AIT; ++it) {
        int s = it * 256 + tid, row = s >> 2, ch = s & 3;
        va[it] = *(const s16x8*)(A + (size_t)(bm + row) * K + k0 + 32 + ch * 8);
      }
#pragma unroll
      for (int it = 0; it < BIT; ++it) {
        int s = it * 256 + tid, row = s >> 2, ch = s & 3;
        vb[it] = *(const s16x8*)(Wt + (size_t)(bn + row) * K + k0 + 32 + ch * 8);
      }
    }
    __syncthreads();
    s16x8 ar[MR], br[NR];
#pragma unroll
    for (int i = 0; i < MR; ++i) {
      int row = r0 + i * 16 + li;
      ar[i] = *(const s16x8*)&As[row * 32 + ((g ^ (row & 3)) * 8)];
    }
#pragma unroll
    for (int j = 0; j < NR; ++j) {
      int row = c0 + j * 16 + li;
      br[j] = *(const s16x8*)&Bs[row * 32 + ((g ^ (row & 3)) * 8)];
    }
#pragma unroll
    for (int i = 0; i < MR; ++i)
#pragma unroll
      for (int j = 0; j < NR; ++j) acc[i][j] = mfma_bf16(ar[i], br[j], acc[i][j]);
  }

#pragma unroll
  for (int j = 0; j < NR; ++j) {
    int col = bn + c0 + j * 16 + li;
    float bv = (bias && col < biasN) ? bias[col] : 0.f;
#pragma unroll
    for (int i = 0; i < MR; ++i) {
#pragma unroll
      for (int r = 0; r < 4; ++r) {
        int rowg = bm + r0 + i * 16 + 4 * g + r;
        float v = acc[i][j][r] + bv;
        if (RELU) v = fmaxf(v, 0.f);
        if (OUT == 0) ((float*)Cout)[(size_t)rowg * N + col] = v;
        else          ((u16*)Cout)[(size_t)rowg * N + col] = f2bf(v);
      }
    }
  }
}

// ---------------------------------------------------------------------------
// Weight transpose+convert: f32 [Ks][Ns] -> bf16 [Ns][Ks] at dstOff
// ---------------------------------------------------------------------------
struct WPtrs { const float* p[10]; };

__global__ __launch_bounds__(256) void wcvt(WPtrs wp, u16* __restrict__ dst) {
  constexpr int NE = 20;
  constexpr int srcIdx[NE] = {0,1,0,1,3,3,4,4,5,5,6,6,7,7,2,2,8,8,9,9};
  constexpr int srcOff[NE] = {0,0,262144,262144,0,262144,0,262144,0,262144,
                              0,262144,0,262144,0,262144,0,1048576,0,1048576};
  constexpr int dstOff[NE] = {0,262144,524288,786432,1048576,1310720,
                              1572864,1835008,2097152,2359296,2621440,2883584,
                              3145728,3407872,3670016,3932160,
                              4194304,5242880,6291456,7340032};
  constexpr int KsA[NE] = {512,512,512,512,512,512,512,512,512,512,
                           512,512,512,512,512,512,512,512,2048,2048};
  constexpr int NsA[NE] = {512,512,512,512,512,512,512,512,512,512,
                           512,512,512,512,512,512,2048,2048,512,512};
  constexpr int tileStart[NE] = {0,64,128,192,256,320,384,448,512,576,
                                 640,704,768,832,896,960,1024,1280,1536,1792};
  __shared__ float ts[64 * 65];
  const int tid = threadIdx.x;
  const int bid = blockIdx.x;
  int e = 0;
#pragma unroll
  for (int i = 1; i < NE; ++i) if (bid >= tileStart[i]) e = i;
  const int t = bid - tileStart[e];
  const int Ks_ = KsA[e], Ns_ = NsA[e];
  const int tn = t % (Ns_ >> 6), tk = t / (Ns_ >> 6);
  const float* src = wp.p[srcIdx[e]] + srcOff[e];

  {
    int r = tid >> 2, cb = (tid & 3) * 16;
    const float* sp = src + (size_t)(tk * 64 + r) * Ns_ + tn * 64 + cb;
#pragma unroll
    for (int j = 0; j < 4; ++j) {
      float4 v = ((const float4*)sp)[j];
      float* d = &ts[r * 65 + cb + j * 4];
      d[0] = v.x; d[1] = v.y; d[2] = v.z; d[3] = v.w;
    }
  }
  __syncthreads();
  {
    int n = tid >> 2, kb = (tid & 3) * 16;
    u16* dp = dst + dstOff[e] + (size_t)(tn * 64 + n) * Ks_ + tk * 64 + kb;
    s16x8 o0, o1;
#pragma unroll
    for (int j = 0; j < 8; ++j) o0[j] = (short)f2bf(ts[(kb + j) * 65 + n]);
#pragma unroll
    for (int j = 0; j < 8; ++j) o1[j] = (short)f2bf(ts[(kb + 8 + j) * 65 + n]);
    *(s16x8*)dp = o0;
    *(s16x8*)(dp + 8) = o1;
  }
}

// ---------------------------------------------------------------------------
// activations f32->bf16 + f32 copy of q (blocks 0..1023); block 1024:
// relv -> relv^T bf16; blocks 1025..1536: rel_ids int32 -> u8 pack.
// ---------------------------------------------------------------------------
__global__ __launch_bounds__(256) void acvt(
    const float* __restrict__ q, const float* __restrict__ kv,
    const float* __restrict__ relv, const int* __restrict__ rel,
    u16* __restrict__ obf, u16* __restrict__ kvbf, u16* __restrict__ relvt,
    u8* __restrict__ rel8, float* __restrict__ ocp) {
  int bid = blockIdx.x, tid = threadIdx.x;
  if (bid >= 1025) {
    size_t i = (size_t)(bid - 1025) * 2048 + (size_t)tid * 8;
    int4 a = *(const int4*)(rel + i);
    int4 b = *(const int4*)(rel + i + 4);
    unsigned lo = (unsigned)(a.x & 255) | ((unsigned)(a.y & 255) << 8) |
                  ((unsigned)(a.z & 255) << 16) | ((unsigned)(a.w & 255) << 24);
    unsigned hi = (unsigned)(b.x & 255) | ((unsigned)(b.y & 255) << 8) |
                  ((unsigned)(b.z & 255) << 16) | ((unsigned)(b.w & 255) << 24);
    *(uint2*)(rel8 + i) = make_uint2(lo, hi);
    return;
  }
  if (bid == 1024) {
    int d = tid >> 2, rb = (tid & 3) * 16;
    s16x8 o0, o1;
#pragma unroll
    for (int j = 0; j < 8; ++j) o0[j] = (short)f2bf(relv[(rb + j) * 64 + d]);
#pragma unroll
    for (int j = 0; j < 8; ++j) o1[j] = (short)f2bf(relv[(rb + 8 + j) * 64 + d]);
    *(s16x8*)(relvt + d * 64 + rb) = o0;
    *(s16x8*)(relvt + d * 64 + rb + 8) = o1;
    return;
  }
  int i = bid * 256 + tid;
  const float* src; u16* dst; size_t off;
  bool isq = (i < 131072);
  if (isq) { src = q; dst = obf; off = (size_t)i * 8; }
  else { src = kv; dst = kvbf; off = (size_t)(i - 131072) * 8; }
  float4 a = *(const float4*)(src + off);
  float4 b = *(const float4*)(src + off + 4);
  if (isq) {
    *(float4*)(ocp + off) = a;
    *(float4*)(ocp + off + 4) = b;
  }
  s16x8 o;
  o[0] = (short)f2bf(a.x); o[1] = (short)f2bf(a.y);
  o[2] = (short)f2bf(a.z); o[3] = (short)f2bf(a.w);
  o[4] = (short)f2bf(b.x); o[5] = (short)f2bf(b.y);
  o[6] = (short)f2bf(b.z); o[7] = (short)f2bf(b.w);
  *(s16x8*)(dst + off) = o;
}

// ---------------------------------------------------------------------------
// Qr[(row*8+h), r] = 0.125 * sum_d Q[row, h*64+d] * relk[r, d]  (bf16 out,
// prescaled so smax adds it directly to prescaled scores)
// ---------------------------------------------------------------------------
__global__ __launch_bounds__(256) void qr_kernel(
    const u16* __restrict__ Q, const float* __restrict__ relk,
    u16* __restrict__ Qr) {
  __shared__ float rk[64 * 65];
  __shared__ float qs[4][64];
  const int tid = threadIdx.x;
  {
    int r = tid >> 2, cb = (tid & 3) * 16;
    const float* sp = relk + r * 64 + cb;
#pragma unroll
    for (int j = 0; j < 4; ++j) {
      float4 v = ((const float4*)sp)[j];
      float* d = &rk[r * 65 + cb + j * 4];
      d[0] = v.x; d[1] = v.y; d[2] = v.z; d[3] = v.w;
    }
  }
  const int sub = tid >> 6, r = tid & 63;
  const int unit = blockIdx.x * 4 + sub;  // unit = row*8 + h
  qs[sub][r] = bf2f(Q[(size_t)(unit >> 3) * 1024 + (unit & 7) * 64 + r]);
  __syncthreads();
  float acc = 0.f;
#pragma unroll
  for (int d = 0; d < 64; ++d) acc += qs[sub][d] * rk[r * 65 + d];
  Qr[(size_t)unit * 64 + r] = f2bf(acc * 0.125f);
}

// ---------------------------------------------------------------------------
// attn_score: batched S[bh][l][m] = 0.125 * Q[l,:] . K[m,:]  (prescaled).
// Grid (4 mtile128, 4 ltile128, 32 bh), 256 thr, 4 waves 2x2 (64x64 each).
// ---------------------------------------------------------------------------
__global__ __launch_bounds__(256) void attn_score(
    const u16* __restrict__ Qb, int qstride,
    const u16* __restrict__ Kb, int kstride,
    u16* __restrict__ S) {
  const int tid = threadIdx.x;
  const int w = tid >> 6, lane = tid & 63, g = lane >> 4, li = lane & 15;
  const int mt = blockIdx.x, lt = blockIdx.y, bh = blockIdx.z;
  const int b = bh >> 3, h = bh & 7;
  const int lbase = lt * 128 + (w & 1) * 64;
  const int mbase = mt * 128 + (w >> 1) * 64;

  s16x8 aq[4][2], bk[4][2];
#pragma unroll
  for (int i = 0; i < 4; ++i) {
    const u16* qp = Qb + (size_t)(b * 512 + lbase + i * 16 + li) * qstride + h * 64;
    aq[i][0] = *(const s16x8*)(qp + g * 8);
    aq[i][1] = *(const s16x8*)(qp + 32 + g * 8);
  }
#pragma unroll
  for (int j = 0; j < 4; ++j) {
    const u16* kp = Kb + (size_t)(b * 512 + mbase + j * 16 + li) * kstride + h * 64;
    bk[j][0] = *(const s16x8*)(kp + g * 8);
    bk[j][1] = *(const s16x8*)(kp + 32 + g * 8);
  }
  f32x4 acc[4][4];
#pragma unroll
  for (int i = 0; i < 4; ++i)
#pragma unroll
    for (int j = 0; j < 4; ++j) {
      acc[i][j] = mfma_bf16(aq[i][0], bk[j][0], (f32x4){0.f, 0.f, 0.f, 0.f});
      acc[i][j] = mfma_bf16(aq[i][1], bk[j][1], acc[i][j]);
    }
  u16* Sb = S + (size_t)bh * 262144;
#pragma unroll
  for (int j = 0; j < 4; ++j)
#pragma unroll
    for (int i = 0; i < 4; ++i)
#pragma unroll
      for (int r = 0; r < 4; ++r)
        Sb[(size_t)(lbase + i * 16 + 4 * g + r) * 512 + mbase + j * 16 + li] =
            f2bf(acc[i][j][r] * 0.125f);
}

// ---------------------------------------------------------------------------
// attn_smax_self: full-row softmax + PAD/causal mask + Qr bias + rel-V
// buckets. NAMED SCALARS ONLY (no local arrays -> no scratch demotion).
// One wave per row. Writes normalized P row (512 bf16) + buckets at 512..575.
// All-masked rows -> all e=NEG -> uniform (exact; bucket0 hits relv[0]=0).
// ---------------------------------------------------------------------------
__global__ __launch_bounds__(256) void attn_smax_self(
    const u16* __restrict__ S, const u8* __restrict__ rel8,
    const u16* __restrict__ Qrb, u16* __restrict__ P) {
  __shared__ float qrs[4][64];
  __shared__ float buck[4][64];
  const int tid = threadIdx.x;
  const int w = tid >> 6, lane = tid & 63;
  const int rowid = blockIdx.x * 4 + w;
  const int bh = rowid >> 9, l = rowid & 511;
  const int b = bh >> 3, h = bh & 7;

  qrs[w][lane] = bf2f(Qrb[((size_t)(b * 512 + l) * 8 + h) * 64 + lane]);
  buck[w][lane] = 0.f;

  s16x8 sv = *(const s16x8*)(S + (size_t)bh * 262144 + (size_t)l * 512 + lane * 8);
  uint2 rv = *(const uint2*)(rel8 + (size_t)(b * 512 + l) * 512 + (size_t)lane * 8);
  const int m0 = lane * 8;
  const int i0 = (int)(rv.x & 255u);
  const int i1 = (int)((rv.x >> 8) & 255u);
  const int i2 = (int)((rv.x >> 16) & 255u);
  const int i3 = (int)((rv.x >> 24) & 255u);
  const int i4 = (int)(rv.y & 255u);
  const int i5 = (int)((rv.y >> 8) & 255u);
  const int i6 = (int)((rv.y >> 16) & 255u);
  const int i7 = (int)((rv.y >> 24) & 255u);

  float e0 = (i0 != 0 && m0 + 0 <= l) ? bf2f((u16)sv[0]) + qrs[w][i0] : NEGV;
  float e1 = (i1 != 0 && m0 + 1 <= l) ? bf2f((u16)sv[1]) + qrs[w][i1] : NEGV;
  float e2 = (i2 != 0 && m0 + 2 <= l) ? bf2f((u16)sv[2]) + qrs[w][i2] : NEGV;
  float e3 = (i3 != 0 && m0 + 3 <= l) ? bf2f((u16)sv[3]) + qrs[w][i3] : NEGV;
  float e4 = (i4 != 0 && m0 + 4 <= l) ? bf2f((u16)sv[4]) + qrs[w][i4] : NEGV;
  float e5 = (i5 != 0 && m0 + 5 <= l) ? bf2f((u16)sv[5]) + qrs[w][i5] : NEGV;
  float e6 = (i6 != 0 && m0 + 6 <= l) ? bf2f((u16)sv[6]) + qrs[w][i6] : NEGV;
  float e7 = (i7 != 0 && m0 + 7 <= l) ? bf2f((u16)sv[7]) + qrs[w][i7] : NEGV;

  float mx = fmaxf(fmaxf(fmaxf(e0, e1), fmaxf(e2, e3)),
                   fmaxf(fmaxf(e4, e5), fmaxf(e6, e7)));
#pragma unroll
  for (int msk = 1; msk < 64; msk <<= 1) mx = fmaxf(mx, __shfl_xor(mx, msk));

  float p0 = __expf(e0 - mx), p1 = __expf(e1 - mx);
  float p2 = __expf(e2 - mx), p3 = __expf(e3 - mx);
  float p4 = __expf(e4 - mx), p5 = __expf(e5 - mx);
  float p6 = __expf(e6 - mx), p7 = __expf(e7 - mx);
  float rs = ((p0 + p1) + (p2 + p3)) + ((p4 + p5) + (p6 + p7));
#pragma unroll
  for (int msk = 1; msk < 64; msk <<= 1) rs += __shfl_xor(rs, msk);

  atomicAdd(&buck[w][i0], p0);
  atomicAdd(&buck[w][i1], p1);
  atomicAdd(&buck[w][i2], p2);
  atomicAdd(&buck[w][i3], p3);
  atomicAdd(&buck[w][i4], p4);
  atomicAdd(&buck[w][i5], p5);
  atomicAdd(&buck[w][i6], p6);
  atomicAdd(&buck[w][i7], p7);

  const float inv = 1.f / rs;
  u16* Pr = P + (size_t)bh * 294912 + (size_t)l * 576;
  s16x8 ov;
  ov[0] = (short)f2bf(p0 * inv); ov[1] = (short)f2bf(p1 * inv);
  ov[2] = (short)f2bf(p2 * inv); ov[3] = (short)f2bf(p3 * inv);
  ov[4] = (short)f2bf(p4 * inv); ov[5] = (short)f2bf(p5 * inv);
  ov[6] = (short)f2bf(p6 * inv); ov[7] = (short)f2bf(p7 * inv);
  *(s16x8*)(Pr + lane * 8) = ov;
  Pr[512 + lane] = f2bf(buck[w][lane] * inv);  // same-wave DS order: safe
}

// ---------------------------------------------------------------------------
// attn_smax_cross: full-row softmax (prescaled S), named scalars only.
// ---------------------------------------------------------------------------
__global__ __launch_bounds__(256) void attn_smax_cross(
    const u16* __restrict__ S, u16* __restrict__ P) {
  const int tid = threadIdx.x;
  const int w = tid >> 6, lane = tid & 63;
  const int rowid = blockIdx.x * 4 + w;
  const int bh = rowid >> 9, l = rowid & 511;

  s16x8 sv = *(const s16x8*)(S + (size_t)bh * 262144 + (size_t)l * 512 + lane * 8);
  float e0 = bf2f((u16)sv[0]), e1 = bf2f((u16)sv[1]);
  float e2 = bf2f((u16)sv[2]), e3 = bf2f((u16)sv[3]);
  float e4 = bf2f((u16)sv[4]), e5 = bf2f((u16)sv[5]);
  float e6 = bf2f((u16)sv[6]), e7 = bf2f((u16)sv[7]);
  float mx = fmaxf(fmaxf(fmaxf(e0, e1), fmaxf(e2, e3)),
                   fmaxf(fmaxf(e4, e5), fmaxf(e6, e7)));
#pragma unroll
  for (int msk = 1; msk < 64; msk <<= 1) mx = fmaxf(mx, __shfl_xor(mx, msk));
  float p0 = __expf(e0 - mx), p1 = __expf(e1 - mx);
  float p2 = __expf(e2 - mx), p3 = __expf(e3 - mx);
  float p4 = __expf(e4 - mx), p5 = __expf(e5 - mx);
  float p6 = __expf(e6 - mx), p7 = __expf(e7 - mx);
  float rs = ((p0 + p1) + (p2 + p3)) + ((p4 + p5) + (p6 + p7));
#pragma unroll
  for (int msk = 1; msk < 64; msk <<= 1) rs += __shfl_xor(rs, msk);
  const float inv = 1.f / rs;
  u16* Pr = P + (size_t)bh * 294912 + (size_t)l * 576;
  s16x8 ov;
  ov[0] = (short)f2bf(p0 * inv); ov[1] = (short)f2bf(p1 * inv);
  ov[2] = (short)f2bf(p2 * inv); ov[3] = (short)f2bf(p3 * inv);
  ov[4] = (short)f2bf(p4 * inv); ov[5] = (short)f2bf(p5 * inv);
  ov[6] = (short)f2bf(p6 * inv); ov[7] = (short)f2bf(p7 * inv);
  *(s16x8*)(Pr + lane * 8) = ov;
}

// ---------------------------------------------------------------------------
// attn_pv: att[l, h*64+d] = sum_k P[l,k] * B[k,d] where B = [V ; relv]
// (K = 576 self incl. rel rows, 512 cross). Grid (8 ltile64, 32 bh), 256 thr,
// 4 waves 2x2, each 32x32.
// ---------------------------------------------------------------------------
template <int KT>  // K-chunks of 32: 18 self, 16 cross
__global__ __launch_bounds__(256) void attn_pv(
    const u16* __restrict__ P, const u16* __restrict__ VT, int vstride,
    const u16* __restrict__ relvt, u16* __restrict__ att) {
  const int tid = threadIdx.x;
  const int w = tid >> 6, lane = tid & 63, g = lane >> 4, li = lane & 15;
  const int lt = blockIdx.x, bh = blockIdx.y;
  const int b = bh >> 3, h = bh & 7;
  const int r0 = (w & 1) * 32, c0 = (w >> 1) * 32;
  const u16* Pb = P + (size_t)bh * 294912;

  f32x4 acc[2][2];
#pragma unroll
  for (int i = 0; i < 2; ++i)
#pragma unroll
    for (int j = 0; j < 2; ++j) acc[i][j] = (f32x4){0.f, 0.f, 0.f, 0.f};

  for (int k0 = 0; k0 < KT * 32; k0 += 32) {
    s16x8 ar[2], br[2];
#pragma unroll
    for (int i = 0; i < 2; ++i) {
      int l = lt * 64 + r0 + i * 16 + li;
      ar[i] = *(const s16x8*)(Pb + (size_t)l * 576 + k0 + g * 8);
    }
#pragma unroll
    for (int j = 0; j < 2; ++j) {
      int n = c0 + j * 16 + li;
      br[j] = (k0 < 512)
          ? *(const s16x8*)(VT + (size_t)(h * 64 + n) * vstride + b * 512 + k0 + g * 8)
          : *(const s16x8*)(relvt + n * 64 + (k0 - 512) + g * 8);
    }
#pragma unroll
    for (int i = 0; i < 2; ++i)
#pragma unroll
      for (int j = 0; j < 2; ++j) acc[i][j] = mfma_bf16(ar[i], br[j], acc[i][j]);
  }
#pragma unroll
  for (int i = 0; i < 2; ++i)
#pragma unroll
    for (int j = 0; j < 2; ++j)
#pragma unroll
      for (int r = 0; r < 4; ++r) {
        int l = lt * 64 + r0 + i * 16 + 4 * g + r;
        int d = c0 + j * 16 + li;
        att[(size_t)(b * 512 + l) * 512 + h * 64 + d] = f2bf(acc[i][j][r]);
      }
}

// ---------------------------------------------------------------------------
// out = LayerNorm(x + dlt) * g + b ; also writes bf16 copy
// ---------------------------------------------------------------------------
__global__ __launch_bounds__(256) void ln_res(
    const float* __restrict__ x, const float* __restrict__ dlt,
    const float* __restrict__ g, const float* __restrict__ bta,
    float* __restrict__ out, u16* __restrict__ obf) {
  __shared__ float red_s[256];
  const int row = blockIdx.x, tid = threadIdx.x;
  const size_t base = (size_t)row * Hc;
  float v0 = x[base + tid] + dlt[base + tid];
  float v1 = x[base + tid + 256] + dlt[base + tid + 256];

  red_s[tid] = v0 + v1;
  __syncthreads();
  for (int s = 128; s > 0; s >>= 1) {
    if (tid < s) red_s[tid] += red_s[tid + s];
    __syncthreads();
  }
  const float mean = red_s[0] * (1.f / Hc);
  __syncthreads();
  const float d0 = v0 - mean, d1 = v1 - mean;
  red_s[tid] = d0 * d0 + d1 * d1;
  __syncthreads();
  for (int s = 128; s > 0; s >>= 1) {
    if (tid < s) red_s[tid] += red_s[tid + s];
    __syncthreads();
  }
  const float rstd = rsqrtf(red_s[0] * (1.f / Hc) + EPSV);
  float o0 = d0 * rstd * g[tid] + bta[tid];
  float o1 = d1 * rstd * g[tid + 256] + bta[tid + 256];
  out[base + tid] = o0;
  out[base + tid + 256] = o1;
  obf[base + tid] = f2bf(o0);
  obf[base + tid + 256] = f2bf(o1);
}

// ---------------------------------------------------------------------------
extern "C" void kernel_launch(void* const* d_in, const int* in_sizes, int n_in,
                              void* d_out, int out_size, void* d_ws, size_t ws_size,
                              hipStream_t stream) {
  const float* q    = (const float*)d_in[0];
  const float* kv   = (const float*)d_in[1];
  const float* relk = (const float*)d_in[2];
  const float* relv = (const float*)d_in[3];
  const float* Wq_s = (const float*)d_in[4];
  const float* bq_s = (const float*)d_in[5];
  const float* Wk_s = (const float*)d_in[6];
  const float* Wv_s = (const float*)d_in[7];
  const float* Wo_s = (const float*)d_in[8];
  const float* bo_s = (const float*)d_in[9];
  const float* ln1g = (const float*)d_in[10];
  const float* ln1b = (const float*)d_in[11];
  const float* Wq_c = (const float*)d_in[12];
  const float* bq_c = (const float*)d_in[13];
  const float* Wk_c = (const float*)d_in[14];
  const float* Wv_c = (const float*)d_in[15];
  const float* Wo_c = (const float*)d_in[16];
  const float* bo_c = (const float*)d_in[17];
  const float* ln2g = (const float*)d_in[18];
  const float* ln2b = (const float*)d_in[19];
  const float* W1   = (const float*)d_in[20];
  const float* b1   = (const float*)d_in[21];
  const float* W2   = (const float*)d_in[22];
  const float* b2   = (const float*)d_in[23];
  const float* ln3g = (const float*)d_in[24];
  const float* ln3b = (const float*)d_in[25];
  const int*   rel  = (const int*)d_in[26];

  char* wsb = (char*)d_ws;
  const size_t NT = (size_t)Bc * Tc;  // 2048 token rows
  float* o     = (float*)wsb;  wsb += NT * Hc * 4;       // 4MB
  float* bDlt  = (float*)wsb;  wsb += NT * Hc * 4;       // 4MB
  u16* Qr      = (u16*)wsb;    wsb += NT * 8 * 64 * 2;   // 2MB (bf16)
  u16* obf     = (u16*)wsb;    wsb += NT * Hc * 2;       // 2MB
  u16* kvbf    = (u16*)wsb;    wsb += NT * Hc * 2;       // 2MB
  u16* bQK     = (u16*)wsb;    wsb += NT * 1024 * 2;     // 4MB
  u16* bVt     = (u16*)wsb;    wsb += (size_t)512 * 2048 * 2;   // 2MB
  u16* bQc     = (u16*)wsb;    wsb += NT * Hc * 2;       // 2MB
  u16* bKc     = (u16*)wsb;    wsb += NT * 1024 * 2;     // 4MB
  u16* bVtc    = (u16*)wsb;    wsb += (size_t)1024 * 2048 * 2;  // 4MB
  u16* bAtt    = (u16*)wsb;    wsb += NT * Hc * 2;       // 2MB
  u16* bH      = (u16*)wsb;    wsb += NT * FFc * 2;      // 8MB
  u16* relvt   = (u16*)wsb;    wsb += 64 * 64 * 2;       // 8KB
  u8* rel8     = (u8*)wsb;     wsb += (size_t)NT * 512;  // 1MB
  u16* wbuf    = (u16*)wsb;    wsb += (size_t)8388608 * 2;  // 16MB
  u16* S       = (u16*)wsb;    wsb += (size_t)32 * 262144 * 2;  // 16MB
  u16* P       = (u16*)wsb;    wsb += (size_t)32 * 294912 * 2;  // 18MB

  WPtrs wp;
  wp.p[0] = Wq_s; wp.p[1] = Wk_s; wp.p[2] = Wv_s; wp.p[3] = Wo_s;
  wp.p[4] = Wq_c; wp.p[5] = Wk_c; wp.p[6] = Wv_c; wp.p[7] = Wo_c;
  wp.p[8] = W1;   wp.p[9] = W2;

  dim3 blk(256);
  wcvt<<<dim3(2048), blk, 0, stream>>>(wp, wbuf);
  acvt<<<dim3(1537), blk, 0, stream>>>(q, kv, relv, rel, obf, kvbf, relvt,
                                       rel8, o);

  // cross K (both layers) and cross V^T (both layers)
  gemm_mfma<64, 128, false, 1><<<dim3(8, 32), blk, 0, stream>>>(
      kvbf, wbuf + 2097152, nullptr, 0, bKc, 1024, 512);
  gemm_mfma<64, 128, false, 1><<<dim3(16, 16), blk, 0, stream>>>(
      wbuf + 2621440, kvbf, nullptr, 0, bVtc, 2048, 512);

  const dim3 gLN(NT);
  const dim3 gSC(4, 4, 32);
  const dim3 gSM(4096);
  const dim3 gPV(8, 32);
  for (int i = 0; i < NLc; ++i) {
    // --- relation-aware masked self-attention ---
    gemm_mfma<64, 128, false, 1><<<dim3(8, 32), blk, 0, stream>>>(
        obf, wbuf + (size_t)i * 524288, bq_s + i * Hc, Hc, bQK, 1024, 512);
    gemm_mfma<64, 64, false, 1><<<dim3(32, 8), blk, 0, stream>>>(
        wbuf + 3670016 + (size_t)i * 262144, obf, nullptr, 0, bVt, 2048, 512);
    qr_kernel<<<dim3(4096), blk, 0, stream>>>(bQK, relk, Qr);
    attn_score<<<gSC, blk, 0, stream>>>(bQK, 1024, bQK + 512, 1024, S);
    attn_smax_self<<<gSM, blk, 0, stream>>>(S, rel8, Qr, P);
    attn_pv<18><<<gPV, blk, 0, stream>>>(P, bVt, 2048, relvt, bAtt);
    gemm_mfma<64, 64, false, 0><<<dim3(8, 32), blk, 0, stream>>>(
        bAtt, wbuf + 1048576 + (size_t)i * 262144, bo_s + i * Hc, Hc, bDlt, Hc, 512);
    ln_res<<<gLN, blk, 0, stream>>>(o, bDlt, ln1g + i * Hc, ln1b + i * Hc, o, obf);

    // --- cross-attention ---
    gemm_mfma<64, 64, false, 1><<<dim3(8, 32), blk, 0, stream>>>(
        obf, wbuf + 1572864 + (size_t)i * 262144, bq_c + i * Hc, Hc, bQc, Hc, 512);
    attn_score<<<gSC, blk, 0, stream>>>(bQc, 512, bKc + i * 512, 1024, S);
    attn_smax_cross<<<gSM, blk, 0, stream>>>(S, P);
    attn_pv<16><<<gPV, blk, 0, stream>>>(
        P, bVtc + (size_t)i * 512 * 2048, 2048, relvt, bAtt);
    gemm_mfma<64, 64, false, 0><<<dim3(8, 32), blk, 0, stream>>>(
        bAtt, wbuf + 3145728 + (size_t)i * 262144, bo_c + i * Hc, Hc, bDlt, Hc, 512);
    ln_res<<<gLN, blk, 0, stream>>>(o, bDlt, ln2g + i * Hc, ln2b + i * Hc, o, obf);

    // --- feedforward ---
    gemm_mfma<64, 128, true, 1><<<dim3(16, 32), blk, 0, stream>>>(
        obf, wbuf + 4194304 + (size_t)i * 1048576, b1 + i * FFc, FFc, bH, FFc, 512);
    gemm_mfma<64, 64, false, 0><<<dim3(8, 32), blk, 0, stream>>>(
        bH, wbuf + 6291456 + (size_t)i * 1048576, b2 + i * Hc, Hc, bDlt, Hc, 2048);
    float* lnout = (i == NLc - 1) ? (float*)d_out : o;
    ln_res<<<gLN, blk, 0, stream>>>(o, bDlt, ln3g + i * Hc, ln3b + i * Hc, lnout, obf);
  }
}

// Round 16
// 366.500 us; speedup vs baseline: 1.1374x; 1.1374x over previous
//
#include <hip/hip_runtime.h>

static constexpr int Hc  = 512;
static constexpr int NHc = 8;
static constexpr int DHc = 64;
static constexpr int NLc = 2;
static constexpr int Rc  = 64;
static constexpr int FFc = 2048;
static constexpr int Bc  = 4;
static constexpr int Tc  = 512;
#define NEGV (-1e10f)
#define EPSV 1e-5f
#define THRV 6.0f

typedef unsigned short u16;
typedef unsigned char u8;
typedef __attribute__((ext_vector_type(8))) short s16x8;
typedef __attribute__((ext_vector_type(4))) float f32x4;

__device__ __forceinline__ f32x4 mfma_bf16(s16x8 a, s16x8 b, f32x4 c) {
  return __builtin_amdgcn_mfma_f32_16x16x32_bf16(a, b, c, 0, 0, 0);
}
__device__ __forceinline__ u16 f2bf(float f) {
  union { float f; unsigned u; } x; x.f = f;
  unsigned r = (x.u + 0x7FFFu + ((x.u >> 16) & 1u)) >> 16;
  return (u16)r;
}
__device__ __forceinline__ float bf2f(u16 h) {
  union { unsigned u; float f; } x; x.u = ((unsigned)h) << 16;
  return x.f;
}
__device__ __forceinline__ unsigned cvtpk(float a, float b) {
  unsigned r;
  asm("v_cvt_pk_bf16_f32 %0, %1, %2" : "=v"(r) : "v"(a), "v"(b));
  return r;
}

// ---------------------------------------------------------------------------
// bf16 MFMA GEMM: C[M,N] = A[M,K] @ Wt[N,K]^T (+bias for col<biasN) (+relu)
// Register double-buffer of the next K-tile.
// ---------------------------------------------------------------------------
template <int BM, int BN, bool RELU, int OUT>  // OUT: 0=f32, 1=bf16
__global__ __launch_bounds__(256) void gemm_mfma(
    const u16* __restrict__ A, const u16* __restrict__ Wt,
    const float* __restrict__ bias, int biasN,
    void* __restrict__ Cout, int N, int K) {
  __shared__ u16 As[BM * 32];
  __shared__ u16 Bs[BN * 32];
  const int tid = threadIdx.x;
  const int w = tid >> 6, lane = tid & 63, g = lane >> 4, li = lane & 15;
  const int bn = blockIdx.x * BN, bm = blockIdx.y * BM;
  const int r0 = (w & 1) * (BM / 2), c0 = (w >> 1) * (BN / 2);
  constexpr int MR = BM / 32, NR = BN / 32;
  constexpr int AIT = BM / 64, BIT = BN / 64;
  f32x4 acc[MR][NR];
#pragma unroll
  for (int i = 0; i < MR; ++i)
#pragma unroll
    for (int j = 0; j < NR; ++j) acc[i][j] = (f32x4){0.f, 0.f, 0.f, 0.f};

  s16x8 va[AIT], vb[BIT];
#pragma unroll
  for (int it = 0; it < AIT; ++it) {
    int s = it * 256 + tid, row = s >> 2, ch = s & 3;
    va[it] = *(const s16x8*)(A + (size_t)(bm + row) * K + ch * 8);
  }
#pragma unroll
  for (int it = 0; it < BIT; ++it) {
    int s = it * 256 + tid, row = s >> 2, ch = s & 3;
    vb[it] = *(const s16x8*)(Wt + (size_t)(bn + row) * K + ch * 8);
  }

  for (int k0 = 0; k0 < K; k0 += 32) {
    __syncthreads();
#pragma unroll
    for (int it = 0; it < AIT; ++it) {
      int s = it * 256 + tid, row = s >> 2, ch = s & 3;
      *(s16x8*)&As[row * 32 + ((ch ^ (row & 3)) * 8)] = va[it];
    }
#pragma unroll
    for (int it = 0; it < BIT; ++it) {
      int s = it * 256 + tid, row = s >> 2, ch = s & 3;
      *(s16x8*)&Bs[row * 32 + ((ch ^ (row & 3)) * 8)] = vb[it];
    }
    if (k0 + 32 < K) {
#pragma unroll
      for (int it = 0; it < AIT; ++it) {
        int s = it * 256 + tid, row = s >> 2, ch = s & 3;
        va[it] = *(const s16x8*)(A + (size_t)(bm + row) * K + k0 + 32 + ch * 8);
      }
#pragma unroll
      for (int it = 0; it < BIT; ++it) {
        int s = it * 256 + tid, row = s >> 2, ch = s & 3;
        vb[it] = *(const s16x8*)(Wt + (size_t)(bn + row) * K + k0 + 32 + ch * 8);
      }
    }
    __syncthreads();
    s16x8 ar[MR], br[NR];
#pragma unroll
    for (int i = 0; i < MR; ++i) {
      int row = r0 + i * 16 + li;
      ar[i] = *(const s16x8*)&As[row * 32 + ((g ^ (row & 3)) * 8)];
    }
#pragma unroll
    for (int j = 0; j < NR; ++j) {
      int row = c0 + j * 16 + li;
      br[j] = *(const s16x8*)&Bs[row * 32 + ((g ^ (row & 3)) * 8)];
    }
#pragma unroll
    for (int i = 0; i < MR; ++i)
#pragma unroll
      for (int j = 0; j < NR; ++j) acc[i][j] = mfma_bf16(ar[i], br[j], acc[i][j]);
  }

#pragma unroll
  for (int j = 0; j < NR; ++j) {
    int col = bn + c0 + j * 16 + li;
    float bv = (bias && col < biasN) ? bias[col] : 0.f;
#pragma unroll
    for (int i = 0; i < MR; ++i) {
#pragma unroll
      for (int r = 0; r < 4; ++r) {
        int rowg = bm + r0 + i * 16 + 4 * g + r;
        float v = acc[i][j][r] + bv;
        if (RELU) v = fmaxf(v, 0.f);
        if (OUT == 0) ((float*)Cout)[(size_t)rowg * N + col] = v;
        else          ((u16*)Cout)[(size_t)rowg * N + col] = f2bf(v);
      }
    }
  }
}

// ---------------------------------------------------------------------------
// prep: fused wcvt (blocks 0..2047) + acvt (blocks 2048..3584).
// wcvt: f32 [Ks][Ns] weights -> bf16 [Ns][Ks]. acvt: activations f32->bf16
// (+f32 copy of q), relv^T, rel_ids u8 pack.
// ---------------------------------------------------------------------------
struct WPtrs { const float* p[10]; };

__global__ __launch_bounds__(256) void prep(
    WPtrs wp, u16* __restrict__ dst,
    const float* __restrict__ q, const float* __restrict__ kv,
    const float* __restrict__ relv, const int* __restrict__ rel,
    u16* __restrict__ obf, u16* __restrict__ kvbf, u16* __restrict__ relvt,
    u8* __restrict__ rel8, float* __restrict__ ocp) {
  __shared__ float ts[64 * 65];
  const int tid = threadIdx.x;
  const int bid0 = blockIdx.x;
  if (bid0 < 2048) {  // ---- wcvt path ----
    constexpr int NE = 20;
    constexpr int srcIdx[NE] = {0,1,0,1,3,3,4,4,5,5,6,6,7,7,2,2,8,8,9,9};
    constexpr int srcOff[NE] = {0,0,262144,262144,0,262144,0,262144,0,262144,
                                0,262144,0,262144,0,262144,0,1048576,0,1048576};
    constexpr int dstOff[NE] = {0,262144,524288,786432,1048576,1310720,
                                1572864,1835008,2097152,2359296,2621440,2883584,
                                3145728,3407872,3670016,3932160,
                                4194304,5242880,6291456,7340032};
    constexpr int KsA[NE] = {512,512,512,512,512,512,512,512,512,512,
                             512,512,512,512,512,512,512,512,2048,2048};
    constexpr int NsA[NE] = {512,512,512,512,512,512,512,512,512,512,
                             512,512,512,512,512,512,2048,2048,512,512};
    constexpr int tileStart[NE] = {0,64,128,192,256,320,384,448,512,576,
                                   640,704,768,832,896,960,1024,1280,1536,1792};
    const int bid = bid0;
    int e = 0;
#pragma unroll
    for (int i = 1; i < NE; ++i) if (bid >= tileStart[i]) e = i;
    const int t = bid - tileStart[e];
    const int Ks_ = KsA[e], Ns_ = NsA[e];
    const int tn = t % (Ns_ >> 6), tk = t / (Ns_ >> 6);
    const float* src = wp.p[srcIdx[e]] + srcOff[e];
    {
      int r = tid >> 2, cb = (tid & 3) * 16;
      const float* sp = src + (size_t)(tk * 64 + r) * Ns_ + tn * 64 + cb;
#pragma unroll
      for (int j = 0; j < 4; ++j) {
        float4 v = ((const float4*)sp)[j];
        float* d = &ts[r * 65 + cb + j * 4];
        d[0] = v.x; d[1] = v.y; d[2] = v.z; d[3] = v.w;
      }
    }
    __syncthreads();
    {
      int n = tid >> 2, kb = (tid & 3) * 16;
      u16* dp = dst + dstOff[e] + (size_t)(tn * 64 + n) * Ks_ + tk * 64 + kb;
      s16x8 o0, o1;
#pragma unroll
      for (int j = 0; j < 8; ++j) o0[j] = (short)f2bf(ts[(kb + j) * 65 + n]);
#pragma unroll
      for (int j = 0; j < 8; ++j) o1[j] = (short)f2bf(ts[(kb + 8 + j) * 65 + n]);
      *(s16x8*)dp = o0;
      *(s16x8*)(dp + 8) = o1;
    }
    return;
  }
  // ---- acvt path ----
  const int bid = bid0 - 2048;  // 0..1536
  if (bid >= 1025) {
    size_t i = (size_t)(bid - 1025) * 2048 + (size_t)tid * 8;
    int4 a = *(const int4*)(rel + i);
    int4 b = *(const int4*)(rel + i + 4);
    unsigned lo = (unsigned)(a.x & 255) | ((unsigned)(a.y & 255) << 8) |
                  ((unsigned)(a.z & 255) << 16) | ((unsigned)(a.w & 255) << 24);
    unsigned hi = (unsigned)(b.x & 255) | ((unsigned)(b.y & 255) << 8) |
                  ((unsigned)(b.z & 255) << 16) | ((unsigned)(b.w & 255) << 24);
    *(uint2*)(rel8 + i) = make_uint2(lo, hi);
    return;
  }
  if (bid == 1024) {
    int d = tid >> 2, rb = (tid & 3) * 16;
    s16x8 o0, o1;
#pragma unroll
    for (int j = 0; j < 8; ++j) o0[j] = (short)f2bf(relv[(rb + j) * 64 + d]);
#pragma unroll
    for (int j = 0; j < 8; ++j) o1[j] = (short)f2bf(relv[(rb + 8 + j) * 64 + d]);
    *(s16x8*)(relvt + d * 64 + rb) = o0;
    *(s16x8*)(relvt + d * 64 + rb + 8) = o1;
    return;
  }
  int i = bid * 256 + tid;
  const float* src; u16* dsta; size_t off;
  bool isq = (i < 131072);
  if (isq) { src = q; dsta = obf; off = (size_t)i * 8; }
  else { src = kv; dsta = kvbf; off = (size_t)(i - 131072) * 8; }
  float4 a = *(const float4*)(src + off);
  float4 b = *(const float4*)(src + off + 4);
  if (isq) {
    *(float4*)(ocp + off) = a;
    *(float4*)(ocp + off + 4) = b;
  }
  s16x8 o;
  o[0] = (short)f2bf(a.x); o[1] = (short)f2bf(a.y);
  o[2] = (short)f2bf(a.z); o[3] = (short)f2bf(a.w);
  o[4] = (short)f2bf(b.x); o[5] = (short)f2bf(b.y);
  o[6] = (short)f2bf(b.z); o[7] = (short)f2bf(b.w);
  *(s16x8*)(dsta + off) = o;
}

// ---------------------------------------------------------------------------
// qrpack: fused qr_kernel (blocks 0..4095) + self pack_frags (4096..4351).
// qr: Qr[(row*8+h), r] = sum_d Q[row,h*64+d]*relk[r,d] (bf16).
// pack: K (stride 1024, = bQK+512) and V^T (stride 2048) -> frag order.
// ---------------------------------------------------------------------------
__global__ __launch_bounds__(256) void qrpack(
    const u16* __restrict__ Q, const float* __restrict__ relk,
    u16* __restrict__ Qr,
    const u16* __restrict__ Kin, const u16* __restrict__ VTin,
    u16* __restrict__ Kf, u16* __restrict__ Vf) {
  const int tid = threadIdx.x;
  const int bid0 = blockIdx.x;
  if (bid0 >= 4096) {  // ---- pack path (256 blocks, 2 items/thread) ----
    const int pb = bid0 - 4096;
    const int c8 = pb & 7, h = (pb >> 3) & 7, b = pb >> 6;
    u16* kdst = Kf + (size_t)((b * 8 + h) * 8 + c8) * 4096;
    u16* vdst = Vf + (size_t)((b * 8 + h) * 8 + c8) * 4096;
#pragma unroll
    for (int i = 0; i < 2; ++i) {
      int s = i * 256 + tid;
      int mt = s >> 7, kk = (s >> 6) & 1, lane = s & 63;
      int g = lane >> 4, li = lane & 15;
      s16x8 kv = *(const s16x8*)(
          Kin + (size_t)(b * 512 + c8 * 64 + mt * 16 + li) * 1024 +
          h * 64 + kk * 32 + g * 8);
      s16x8 vv = *(const s16x8*)(
          VTin + (size_t)(h * 64 + mt * 16 + li) * 2048 +
          b * 512 + c8 * 64 + kk * 32 + g * 8);
      *(s16x8*)(kdst + (mt * 2 + kk) * 512 + lane * 8) = kv;
      *(s16x8*)(vdst + (mt * 2 + kk) * 512 + lane * 8) = vv;
    }
    return;
  }
  // ---- qr path ----
  __shared__ float rk[64 * 65];
  __shared__ float qs[4][64];
  {
    int r = tid >> 2, cb = (tid & 3) * 16;
    const float* sp = relk + r * 64 + cb;
#pragma unroll
    for (int j = 0; j < 4; ++j) {
      float4 v = ((const float4*)sp)[j];
      float* d = &rk[r * 65 + cb + j * 4];
      d[0] = v.x; d[1] = v.y; d[2] = v.z; d[3] = v.w;
    }
  }
  const int sub = tid >> 6, r = tid & 63;
  const int unit = bid0 * 4 + sub;  // unit = row*8 + h
  qs[sub][r] = bf2f(Q[(size_t)(unit >> 3) * 1024 + (unit & 7) * 64 + r]);
  __syncthreads();
  float acc = 0.f;
#pragma unroll
  for (int d = 0; d < 64; ++d) acc += qs[sub][d] * rk[r * 65 + d];
  Qr[(size_t)unit * 64 + r] = f2bf(acc);
}

// ---------------------------------------------------------------------------
// pack_cross: both layers' cross K/V^T -> frag order. Grid (8 c8, 8 h, 8 lb)
// where lb = lay*4 + b.
// ---------------------------------------------------------------------------
__global__ __launch_bounds__(128) void pack_cross(
    const u16* __restrict__ Kc,   // [2048][1024], layer at col lay*512
    const u16* __restrict__ VTc,  // [2048][2048], layer at row lay*512
    u16* __restrict__ Kf0, u16* __restrict__ Vf0) {
  const int t = threadIdx.x;
  const int c8 = blockIdx.x, h = blockIdx.y;
  const int lay = blockIdx.z >> 2, b = blockIdx.z & 3;
  const u16* Kin = Kc + lay * 512;
  const u16* VTin = VTc + (size_t)lay * 512 * 2048;
  u16* kdst = Kf0 + (size_t)lay * 2097152 + (size_t)((b * 8 + h) * 8 + c8) * 4096;
  u16* vdst = Vf0 + (size_t)lay * 2097152 + (size_t)((b * 8 + h) * 8 + c8) * 4096;
#pragma unroll
  for (int i = 0; i < 4; ++i) {
    int s = i * 128 + t;
    int mt = s >> 7, kk = (s >> 6) & 1, lane = s & 63;
    int g = lane >> 4, li = lane & 15;
    s16x8 kv = *(const s16x8*)(
        Kin + (size_t)(b * 512 + c8 * 64 + mt * 16 + li) * 1024 +
        h * 64 + kk * 32 + g * 8);
    s16x8 vv = *(const s16x8*)(
        VTin + (size_t)(h * 64 + mt * 16 + li) * 2048 +
        b * 512 + c8 * 64 + kk * 32 + g * 8);
    *(s16x8*)(kdst + (mt * 2 + kk) * 512 + lane * 8) = kv;
    *(s16x8*)(vdst + (mt * 2 + kk) * 512 + lane * 8) = vv;
  }
}

// ---------------------------------------------------------------------------
// FUSED single-wave attention: one wave per (qt,h,b) 16-q-row tile loops all
// 8 chunks with online softmax (defer-rescale THR). No merge, no partials.
// Masked cols give p=exp(NEGV-NEGV)=1 while mrow stays NEGV -> exact uniform
// softmax for all-masked rows (reference semantics); buckets get every col's
// rel id in that case, matching the reference's unmasked rel_v gather.
// ---------------------------------------------------------------------------
#define LOADKREL(KF, RF, C8) do {                                              \
    _Pragma("unroll") for (int mt = 0; mt < 4; ++mt) {                         \
      KF[mt * 2 + 0] = *(const s16x8*)(kfb + (size_t)(C8) * 4096 + (mt * 2 + 0) * 512 + lane * 8); \
      KF[mt * 2 + 1] = *(const s16x8*)(kfb + (size_t)(C8) * 4096 + (mt * 2 + 1) * 512 + lane * 8); \
      RF[mt] = *(const unsigned*)(rp8 + (C8) * 64 + mt * 16);                  \
    } } while (0)

#define COMPUTE_SELF(KF, RF, C8) do {                                          \
    s16x8 vf[8];                                                               \
    _Pragma("unroll") for (int df = 0; df < 4; ++df) {                         \
      vf[df * 2 + 0] = *(const s16x8*)(vfb + (size_t)(C8) * 4096 + (df * 2 + 0) * 512 + lane * 8); \
      vf[df * 2 + 1] = *(const s16x8*)(vfb + (size_t)(C8) * 4096 + (df * 2 + 1) * 512 + lane * 8); } \
    f32x4 sf[4];                                                               \
    _Pragma("unroll") for (int mt = 0; mt < 4; ++mt) {                         \
      sf[mt] = (f32x4){0.f, 0.f, 0.f, 0.f};                                    \
      sf[mt] = mfma_bf16(KF[mt * 2 + 0], aq0, sf[mt]);                         \
      sf[mt] = mfma_bf16(KF[mt * 2 + 1], aq1, sf[mt]); }                       \
    float p[4][4];                                                             \
    int rl[4][4];                                                              \
    float pmax = NEGV;                                                         \
    _Pragma("unroll") for (int mt = 0; mt < 4; ++mt) {                         \
      _Pragma("unroll") for (int r = 0; r < 4; ++r) {                          \
        int rel = (int)((RF[mt] >> (8 * r)) & 255u);                           \
        rl[mt][r] = rel;                                                       \
        bool valid = (rel != 0) && ((C8) * 64 + mt * 16 + 4 * g + r <= lrow);  \
        p[mt][r] = valid ? (sf[mt][r] + qrs[li * 66 + rel]) * 0.125f : NEGV;   \
        pmax = fmaxf(pmax, p[mt][r]); } }                                      \
    pmax = fmaxf(pmax, __shfl_xor(pmax, 16));                                  \
    pmax = fmaxf(pmax, __shfl_xor(pmax, 32));                                  \
    if (__any(pmax > mrow + THRV)) {                                           \
      float mnew = (pmax > mrow + THRV) ? pmax : mrow;                         \
      float f = __expf(mrow - mnew);                                           \
      rsum *= f;                                                               \
      _Pragma("unroll") for (int j = 0; j < 8; ++j) {                          \
        float2* p2 = (float2*)&bk[li * 66 + g * 16 + 2 * j];                   \
        float2 v = *p2; v.x *= f; v.y *= f; *p2 = v; }                         \
      _Pragma("unroll") for (int r = 0; r < 4; ++r) {                          \
        float fr = __shfl(f, 4 * g + r);                                       \
        _Pragma("unroll") for (int df = 0; df < 4; ++df) oacc[df][r] *= fr; }  \
      mrow = mnew; }                                                           \
    unsigned pk[4][2];                                                         \
    _Pragma("unroll") for (int mt = 0; mt < 4; ++mt) {                         \
      _Pragma("unroll") for (int r = 0; r < 4; ++r) {                          \
        float pv = __expf(p[mt][r] - mrow);                                    \
        p[mt][r] = pv;                                                         \
        rsum += pv;                                                            \
        if (pv > 0.f) atomicAdd(&bk[li * 66 + rl[mt][r]], pv); }               \
      pk[mt][0] = cvtpk(p[mt][0], p[mt][1]);                                   \
      pk[mt][1] = cvtpk(p[mt][2], p[mt][3]); }                                 \
    _Pragma("unroll") for (int kk = 0; kk < 2; ++kk) {                         \
      union { s16x8 v; unsigned u[4]; } pa;                                    \
      _Pragma("unroll") for (int q = 0; q < 4; ++q) {                          \
        int src = ((2 * (g & 1) + (q >> 1)) << 4) + li;                        \
        unsigned uA = __shfl(pk[2 * kk][q & 1], src);                          \
        unsigned uB = __shfl(pk[2 * kk + 1][q & 1], src);                      \
        pa.u[q] = (g < 2) ? uA : uB; }                                         \
      _Pragma("unroll") for (int df = 0; df < 4; ++df)                         \
        oacc[df] = mfma_bf16(pa.v, vf[df * 2 + kk], oacc[df]); }               \
  } while (0)

__global__ __launch_bounds__(64) void attn_self(
    const u16* __restrict__ Qb,                              // stride 1024
    const u16* __restrict__ Kf, const u16* __restrict__ Vf,  // frag-packed
    const u16* __restrict__ Qrb, const u8* __restrict__ rel8,
    const u16* __restrict__ relvt, u16* __restrict__ att) {
  __shared__ float qrs[16 * 66];
  __shared__ float buck[16 * 66];
  float* bk = buck;

  const int lane = threadIdx.x;
  const int g = lane >> 4, li = lane & 15;
  const int qt = blockIdx.x, h = blockIdx.y, b = blockIdx.z;
  const int lrow = qt * 16 + li;
  const int growq = b * 512 + qt * 16;

  const u16* qp = Qb + (size_t)(growq + li) * 1024 + h * 64;
  s16x8 aq0 = *(const s16x8*)(qp + g * 8);
  s16x8 aq1 = *(const s16x8*)(qp + 32 + g * 8);
  const u16* kfb = Kf + (size_t)((b * 8 + h) * 8) * 4096;
  const u16* vfb = Vf + (size_t)((b * 8 + h) * 8) * 4096;
  const u8* rp8 = rel8 + (size_t)(growq + li) * 512 + 4 * g;

  {  // stage Qr (bf16 -> f32 LDS) + zero buckets
    int row = lane >> 2, c16 = (lane & 3) * 16;
    const u16* qrp = Qrb + ((size_t)(growq + row) * 8 + h) * 64 + c16;
    s16x8 v0 = *(const s16x8*)qrp;
    s16x8 v1 = *(const s16x8*)(qrp + 8);
#pragma unroll
    for (int j = 0; j < 8; ++j) {
      qrs[row * 66 + c16 + j] = bf2f((u16)v0[j]);
      qrs[row * 66 + c16 + 8 + j] = bf2f((u16)v1[j]);
    }
#pragma unroll
    for (int j = 0; j < 5; ++j) {  // 264 float4s cover 16*66
      int fid = j * 64 + lane;
      if (fid < 264) *(float4*)&buck[fid * 4] = make_float4(0.f, 0.f, 0.f, 0.f);
    }
  }

  float mrow = NEGV, rsum = 0.f;
  f32x4 oacc[4];
#pragma unroll
  for (int d = 0; d < 4; ++d) oacc[d] = (f32x4){0.f, 0.f, 0.f, 0.f};

  for (int c = 0; c < 8; ++c) {  // online softmax over all chunks
    s16x8 kA[8];
    unsigned rA[4];
    LOADKREL(kA, rA, c);
    COMPUTE_SELF(kA, rA, c);
  }

  rsum += __shfl_xor(rsum, 16);
  rsum += __shfl_xor(rsum, 32);

  // rel-V: oacc += buck @ relv  (B = relv^T)
#pragma unroll
  for (int kk = 0; kk < 2; ++kk) {
    float bb[8];
#pragma unroll
    for (int j = 0; j < 4; ++j) {
      float2 v = *(const float2*)&bk[li * 66 + kk * 32 + g * 8 + 2 * j];
      bb[2 * j] = v.x; bb[2 * j + 1] = v.y;
    }
    union { s16x8 v; unsigned u[4]; } pb;
#pragma unroll
    for (int q = 0; q < 4; ++q) pb.u[q] = cvtpk(bb[2 * q], bb[2 * q + 1]);
#pragma unroll
    for (int df = 0; df < 4; ++df) {
      s16x8 rb = *(const s16x8*)(relvt + (df * 16 + li) * 64 + kk * 32 + g * 8);
      oacc[df] = mfma_bf16(pb.v, rb, oacc[df]);
    }
  }

  float inv[4];
#pragma unroll
  for (int r = 0; r < 4; ++r) inv[r] = 1.f / __shfl(rsum, 4 * g + r);
#pragma unroll
  for (int df = 0; df < 4; ++df)
#pragma unroll
    for (int r = 0; r < 4; ++r)
      att[(size_t)(growq + 4 * g + r) * 512 + h * 64 + df * 16 + li] =
          f2bf(oacc[df][r] * inv[r]);
}

#define LOADK_X(KF, C8) do {                                                   \
    _Pragma("unroll") for (int mt = 0; mt < 4; ++mt) {                         \
      KF[mt * 2 + 0] = *(const s16x8*)(kfb + (size_t)(C8) * 4096 + (mt * 2 + 0) * 512 + lane * 8); \
      KF[mt * 2 + 1] = *(const s16x8*)(kfb + (size_t)(C8) * 4096 + (mt * 2 + 1) * 512 + lane * 8); \
    } } while (0)

#define COMPUTE_X(KF, C8) do {                                                 \
    s16x8 vf[8];                                                               \
    _Pragma("unroll") for (int df = 0; df < 4; ++df) {                         \
      vf[df * 2 + 0] = *(const s16x8*)(vfb + (size_t)(C8) * 4096 + (df * 2 + 0) * 512 + lane * 8); \
      vf[df * 2 + 1] = *(const s16x8*)(vfb + (size_t)(C8) * 4096 + (df * 2 + 1) * 512 + lane * 8); } \
    f32x4 sf[4];                                                               \
    _Pragma("unroll") for (int mt = 0; mt < 4; ++mt) {                         \
      sf[mt] = (f32x4){0.f, 0.f, 0.f, 0.f};                                    \
      sf[mt] = mfma_bf16(KF[mt * 2 + 0], aq0, sf[mt]);                         \
      sf[mt] = mfma_bf16(KF[mt * 2 + 1], aq1, sf[mt]); }                       \
    float p[4][4];                                                             \
    float pmax = NEGV;                                                         \
    _Pragma("unroll") for (int mt = 0; mt < 4; ++mt)                           \
      _Pragma("unroll") for (int r = 0; r < 4; ++r) {                          \
        p[mt][r] = sf[mt][r] * 0.125f;                                         \
        pmax = fmaxf(pmax, p[mt][r]); }                                        \
    pmax = fmaxf(pmax, __shfl_xor(pmax, 16));                                  \
    pmax = fmaxf(pmax, __shfl_xor(pmax, 32));                                  \
    if (__any(pmax > mrow + THRV)) {                                           \
      float mnew = (pmax > mrow + THRV) ? pmax : mrow;                         \
      float f = __expf(mrow - mnew);                                           \
      rsum *= f;                                                               \
      _Pragma("unroll") for (int r = 0; r < 4; ++r) {                          \
        float fr = __shfl(f, 4 * g + r);                                       \
        _Pragma("unroll") for (int df = 0; df < 4; ++df) oacc[df][r] *= fr; }  \
      mrow = mnew; }                                                           \
    unsigned pk[4][2];                                                         \
    _Pragma("unroll") for (int mt = 0; mt < 4; ++mt) {                         \
      _Pragma("unroll") for (int r = 0; r < 4; ++r) {                          \
        float pv = __expf(p[mt][r] - mrow);                                    \
        p[mt][r] = pv;                                                         \
        rsum += pv; }                                                          \
      pk[mt][0] = cvtpk(p[mt][0], p[mt][1]);                                   \
      pk[mt][1] = cvtpk(p[mt][2], p[mt][3]); }                                 \
    _Pragma("unroll") for (int kk = 0; kk < 2; ++kk) {                         \
      union { s16x8 v; unsigned u[4]; } pa;                                    \
      _Pragma("unroll") for (int q = 0; q < 4; ++q) {                          \
        int src = ((2 * (g & 1) + (q >> 1)) << 4) + li;                        \
        unsigned uA = __shfl(pk[2 * kk][q & 1], src);                          \
        unsigned uB = __shfl(pk[2 * kk + 1][q & 1], src);                      \
        pa.u[q] = (g < 2) ? uA : uB; }                                         \
      _Pragma("unroll") for (int df = 0; df < 4; ++df)                         \
        oacc[df] = mfma_bf16(pa.v, vf[df * 2 + kk], oacc[df]); }               \
  } while (0)

__global__ __launch_bounds__(64) void attn_cross(
    const u16* __restrict__ Qb,                              // stride 512
    const u16* __restrict__ Kf, const u16* __restrict__ Vf,  // frag-packed
    u16* __restrict__ att) {
  const int lane = threadIdx.x;
  const int g = lane >> 4, li = lane & 15;
  const int qt = blockIdx.x, h = blockIdx.y, b = blockIdx.z;
  const int growq = b * 512 + qt * 16;

  const u16* qp = Qb + (size_t)(growq + li) * 512 + h * 64;
  s16x8 aq0 = *(const s16x8*)(qp + g * 8);
  s16x8 aq1 = *(const s16x8*)(qp + 32 + g * 8);
  const u16* kfb = Kf + (size_t)((b * 8 + h) * 8) * 4096;
  const u16* vfb = Vf + (size_t)((b * 8 + h) * 8) * 4096;

  float mrow = NEGV, rsum = 0.f;
  f32x4 oacc[4];
#pragma unroll
  for (int d = 0; d < 4; ++d) oacc[d] = (f32x4){0.f, 0.f, 0.f, 0.f};

  for (int c = 0; c < 8; ++c) {
    s16x8 kA[8];
    LOADK_X(kA, c);
    COMPUTE_X(kA, c);
  }

  rsum += __shfl_xor(rsum, 16);
  rsum += __shfl_xor(rsum, 32);
  float inv[4];
#pragma unroll
  for (int r = 0; r < 4; ++r) inv[r] = 1.f / __shfl(rsum, 4 * g + r);
#pragma unroll
  for (int df = 0; df < 4; ++df)
#pragma unroll
    for (int r = 0; r < 4; ++r)
      att[(size_t)(growq + 4 * g + r) * 512 + h * 64 + df * 16 + li] =
          f2bf(oacc[df][r] * inv[r]);
}

// ---------------------------------------------------------------------------
// out = LayerNorm(x + dlt) * g + b ; also writes bf16 copy
// ---------------------------------------------------------------------------
__global__ __launch_bounds__(256) void ln_res(
    const float* __restrict__ x, const float* __restrict__ dlt,
    const float* __restrict__ g, const float* __restrict__ bta,
    float* __restrict__ out, u16* __restrict__ obf) {
  __shared__ float red_s[256];
  const int row = blockIdx.x, tid = threadIdx.x;
  const size_t base = (size_t)row * Hc;
  float v0 = x[base + tid] + dlt[base + tid];
  float v1 = x[base + tid + 256] + dlt[base + tid + 256];

  red_s[tid] = v0 + v1;
  __syncthreads();
  for (int s = 128; s > 0; s >>= 1) {
    if (tid < s) red_s[tid] += red_s[tid + s];
    __syncthreads();
  }
  const float mean = red_s[0] * (1.f / Hc);
  __syncthreads();
  const float d0 = v0 - mean, d1 = v1 - mean;
  red_s[tid] = d0 * d0 + d1 * d1;
  __syncthreads();
  for (int s = 128; s > 0; s >>= 1) {
    if (tid < s) red_s[tid] += red_s[tid + s];
    __syncthreads();
  }
  const float rstd = rsqrtf(red_s[0] * (1.f / Hc) + EPSV);
  float o0 = d0 * rstd * g[tid] + bta[tid];
  float o1 = d1 * rstd * g[tid + 256] + bta[tid + 256];
  out[base + tid] = o0;
  out[base + tid + 256] = o1;
  obf[base + tid] = f2bf(o0);
  obf[base + tid + 256] = f2bf(o1);
}

// ---------------------------------------------------------------------------
extern "C" void kernel_launch(void* const* d_in, const int* in_sizes, int n_in,
                              void* d_out, int out_size, void* d_ws, size_t ws_size,
                              hipStream_t stream) {
  const float* q    = (const float*)d_in[0];
  const float* kv   = (const float*)d_in[1];
  const float* relk = (const float*)d_in[2];
  const float* relv = (const float*)d_in[3];
  const float* Wq_s = (const float*)d_in[4];
  const float* bq_s = (const float*)d_in[5];
  const float* Wk_s = (const float*)d_in[6];
  const float* Wv_s = (const float*)d_in[7];
  const float* Wo_s = (const float*)d_in[8];
  const float* bo_s = (const float*)d_in[9];
  const float* ln1g = (const float*)d_in[10];
  const float* ln1b = (const float*)d_in[11];
  const float* Wq_c = (const float*)d_in[12];
  const float* bq_c = (const float*)d_in[13];
  const float* Wk_c = (const float*)d_in[14];
  const float* Wv_c = (const float*)d_in[15];
  const float* Wo_c = (const float*)d_in[16];
  const float* bo_c = (const float*)d_in[17];
  const float* ln2g = (const float*)d_in[18];
  const float* ln2b = (const float*)d_in[19];
  const float* W1   = (const float*)d_in[20];
  const float* b1   = (const float*)d_in[21];
  const float* W2   = (const float*)d_in[22];
  const float* b2   = (const float*)d_in[23];
  const float* ln3g = (const float*)d_in[24];
  const float* ln3b = (const float*)d_in[25];
  const int*   rel  = (const int*)d_in[26];

  char* wsb = (char*)d_ws;
  const size_t NT = (size_t)Bc * Tc;  // 2048 token rows
  float* o     = (float*)wsb;  wsb += NT * Hc * 4;       // 4MB
  float* bDlt  = (float*)wsb;  wsb += NT * Hc * 4;       // 4MB
  u16* Qr      = (u16*)wsb;    wsb += NT * 8 * 64 * 2;   // 2MB (bf16)
  u16* obf     = (u16*)wsb;    wsb += NT * Hc * 2;       // 2MB
  u16* kvbf    = (u16*)wsb;    wsb += NT * Hc * 2;       // 2MB
  u16* bQK     = (u16*)wsb;    wsb += NT * 1024 * 2;     // 4MB
  u16* bVt     = (u16*)wsb;    wsb += (size_t)512 * 2048 * 2;   // 2MB
  u16* bQc     = (u16*)wsb;    wsb += NT * Hc * 2;       // 2MB
  u16* bKc     = (u16*)wsb;    wsb += NT * 1024 * 2;     // 4MB
  u16* bVtc    = (u16*)wsb;    wsb += (size_t)1024 * 2048 * 2;  // 4MB
  u16* bAtt    = (u16*)wsb;    wsb += NT * Hc * 2;       // 2MB
  u16* bH      = (u16*)wsb;    wsb += NT * FFc * 2;      // 8MB
  u16* relvt   = (u16*)wsb;    wsb += 64 * 64 * 2;       // 8KB
  u8* rel8     = (u8*)wsb;     wsb += (size_t)NT * 512;  // 1MB
  u16* wbuf    = (u16*)wsb;    wsb += (size_t)8388608 * 2;  // 16MB
  u16* KfX0    = (u16*)wsb;    wsb += (size_t)1048576 * 2;  // 2MB
  u16* VfX0    = (u16*)wsb;    wsb += (size_t)1048576 * 2;  // 2MB
  u16* KfX1    = (u16*)wsb;    wsb += (size_t)1048576 * 2;  // 2MB
  u16* VfX1    = (u16*)wsb;    wsb += (size_t)1048576 * 2;  // 2MB
  // self frags alias bH (dead outside FFN; repacked per layer before attn)
  u16* KfS     = bH;
  u16* VfS     = bH + 1048576;

  WPtrs wp;
  wp.p[0] = Wq_s; wp.p[1] = Wk_s; wp.p[2] = Wv_s; wp.p[3] = Wo_s;
  wp.p[4] = Wq_c; wp.p[5] = Wk_c; wp.p[6] = Wv_c; wp.p[7] = Wo_c;
  wp.p[8] = W1;   wp.p[9] = W2;

  dim3 blk(256);
  prep<<<dim3(3585), blk, 0, stream>>>(wp, wbuf, q, kv, relv, rel,
                                       obf, kvbf, relvt, rel8, o);

  // cross K (both layers) and cross V^T (both layers), then frag-pack both
  gemm_mfma<64, 128, false, 1><<<dim3(8, 32), blk, 0, stream>>>(
      kvbf, wbuf + 2097152, nullptr, 0, bKc, 1024, 512);
  gemm_mfma<64, 128, false, 1><<<dim3(16, 16), blk, 0, stream>>>(
      wbuf + 2621440, kvbf, nullptr, 0, bVtc, 2048, 512);
  pack_cross<<<dim3(8, 8, 8), dim3(128), 0, stream>>>(bKc, bVtc, KfX0, VfX0);

  const dim3 gLN(NT);
  const dim3 gATT(32, 8, 4);
  for (int i = 0; i < NLc; ++i) {
    // --- relation-aware masked self-attention ---
    gemm_mfma<64, 128, false, 1><<<dim3(8, 32), blk, 0, stream>>>(
        obf, wbuf + (size_t)i * 524288, bq_s + i * Hc, Hc, bQK, 1024, 512);
    gemm_mfma<64, 64, false, 1><<<dim3(32, 8), blk, 0, stream>>>(
        wbuf + 3670016 + (size_t)i * 262144, obf, nullptr, 0, bVt, 2048, 512);
    qrpack<<<dim3(4352), blk, 0, stream>>>(bQK, relk, Qr, bQK + 512, bVt,
                                           KfS, VfS);
    attn_self<<<gATT, dim3(64), 0, stream>>>(
        bQK, KfS, VfS, Qr, rel8, relvt, bAtt);
    gemm_mfma<64, 64, false, 0><<<dim3(8, 32), blk, 0, stream>>>(
        bAtt, wbuf + 1048576 + (size_t)i * 262144, bo_s + i * Hc, Hc, bDlt, Hc, 512);
    ln_res<<<gLN, blk, 0, stream>>>(o, bDlt, ln1g + i * Hc, ln1b + i * Hc, o, obf);

    // --- cross-attention ---
    gemm_mfma<64, 64, false, 1><<<dim3(8, 32), blk, 0, stream>>>(
        obf, wbuf + 1572864 + (size_t)i * 262144, bq_c + i * Hc, Hc, bQc, Hc, 512);
    attn_cross<<<gATT, dim3(64), 0, stream>>>(
        bQc, i ? (KfX0 + 2097152) : KfX0, i ? (VfX0 + 2097152) : VfX0, bAtt);
    gemm_mfma<64, 64, false, 0><<<dim3(8, 32), blk, 0, stream>>>(
        bAtt, wbuf + 3145728 + (size_t)i * 262144, bo_c + i * Hc, Hc, bDlt, Hc, 512);
    ln_res<<<gLN, blk, 0, stream>>>(o, bDlt, ln2g + i * Hc, ln2b + i * Hc, o, obf);

    // --- feedforward ---
    gemm_mfma<64, 128, true, 1><<<dim3(16, 32), blk, 0, stream>>>(
        obf, wbuf + 4194304 + (size_t)i * 1048576, b1 + i * FFc, FFc, bH, FFc, 512);
    gemm_mfma<64, 64, false, 0><<<dim3(8, 32), blk, 0, stream>>>(
        bH, wbuf + 6291456 + (size_t)i * 1048576, b2 + i * Hc, Hc, bDlt, Hc, 2048);
    float* lnout = (i == NLc - 1) ? (float*)d_out : o;
    ln_res<<<gLN, blk, 0, stream>>>(o, bDlt, ln3g + i * Hc, ln3b + i * Hc, lnout, obf);
  }
}